// Round 3
// baseline (187.771 us; speedup 1.0000x reference)
//
#include <hip/hip_runtime.h>
#include <string.h>

// TSM_6330781795061: output = input, except
//   channels [0,21)  zeroed where t == 0   (t = b % 180, 8 clips of 180)
//   channels [21,42) zeroed where t == 179
// Shapes: (1440, 64, 36, 36) fp32. Only 336 of 92,160 planes are zeroed
// (8 clips x {t=0: c in [0,21), t=179: c in [21,42)}) = 1.7 MB.
//
// Strategy: vendor blit (hipMemcpyAsync D2D, tuned to the ~6.3 TB/s copy
// ceiling) for the whole buffer, then a tiny fixup kernel that zeroes the
// 336 planes. Same stream -> ordered. Extra traffic: 0.2%.

typedef float f32x4 __attribute__((ext_vector_type(4)));

constexpr unsigned kTime    = 180;
constexpr unsigned kFold    = 21;          // 64/3
constexpr unsigned kHW4     = 324;         // 36*36/4 float4 per plane
constexpr unsigned kPlanes  = 8u * 2u * kFold;        // 336 planes to zero
constexpr unsigned kZero4   = kPlanes * kHW4;         // 108,864 float4 stores
constexpr size_t   kBytes   = 1440ull * 64ull * 36ull * 36ull * 4ull;  // 478 MB

__global__ __launch_bounds__(256)
void tsm_zero_fixup(f32x4* __restrict__ out) {
    unsigned j = blockIdx.x * 256u + threadIdx.x;
    if (j >= kZero4) return;
    unsigned plane_idx = j / kHW4;       // [0, 336)
    unsigned q         = j % kHW4;
    unsigned n = plane_idx / (2u * kFold);   // clip [0,8)
    unsigned r = plane_idx % (2u * kFold);   // [0,42): r<21 -> t=0, else t=179
    unsigned b = n * kTime + (r < kFold ? 0u : kTime - 1u);
    unsigned c = r;                          // c==r in both halves
    out[(b * 64u + c) * kHW4 + q] = f32x4{0.f, 0.f, 0.f, 0.f};
}

extern "C" void kernel_launch(void* const* d_in, const int* in_sizes, int n_in,
                              void* d_out, int out_size, void* d_ws, size_t ws_size,
                              hipStream_t stream) {
    hipMemcpyAsync(d_out, d_in[0], kBytes, hipMemcpyDeviceToDevice, stream);
    const unsigned grid = (kZero4 + 255u) / 256u;   // 426 blocks
    tsm_zero_fixup<<<grid, 256, 0, stream>>>((f32x4*)d_out);
}